// Round 5
// baseline (168.703 us; speedup 1.0000x reference)
//
#include <hip/hip_runtime.h>

#define B_SZ 8
#define N_SZ 65536
#define C_SZ 128
#define K_SZ 15
#define THREADS 256
#define WAVES 4
#define ROWS 8            // c-rows per wave
#define C_BLK 32          // c-rows per block (WAVES*ROWS)
#define G 4               // c-groups (C_SZ / C_BLK)
#define W_STEP 256        // n per step (64 lanes x float4)
#define S_SPANS 32        // n-spans per batch
#define NSPAN 2048        // N_SZ / S_SPANS
#define STEPS 8           // NSPAN / W_STEP
#define PART_PER_BLK (C_BLK * K_SZ)   // 480
#define INV_KP_EXTENT (1.0f / 0.48f)

// Block = (b, cg, s): 32 c-rows [cg*32, cg*32+32) over n-span [s*2048, (s+1)*2048).
// Every x wave-load is one contiguous 1KB segment (lane*16B) -> full-BW streaming;
// no power-of-2 scatter. Weight table w[k][256] recomputed per block (x4 redundant,
// cheap) into double-buffered LDS. 2-deep register prefetch on x (xA/xB).

__global__ __launch_bounds__(THREADS, 2) void kpconv_main(
    const float* __restrict__ p, const float* __restrict__ x,
    const float* __restrict__ kp, float* __restrict__ part) {
  __shared__ float wt[2][K_SZ][W_STEP];   // 30 KB
  __shared__ float kps[K_SZ * 3];

  const int tid = threadIdx.x;
  const int blk = blockIdx.x;               // ((b*G)+cg)*S_SPANS + s
  const int b  = blk / (G * S_SPANS);
  const int cg = (blk / S_SPANS) % G;
  const int s  = blk % S_SPANS;
  const int nbase = s * NSPAN;

  if (tid < K_SZ * 3) kps[tid] = kp[tid];

  const int lane = tid & 63;
  const int wid  = __builtin_amdgcn_readfirstlane(tid >> 6);

  const float* pb = p + (size_t)b * N_SZ * 3 + (size_t)nbase * 3;
  const float* xrow0 = x + (size_t)b * C_SZ * N_SZ
                         + (size_t)(cg * C_BLK + wid * ROWS) * N_SZ + nbase;

  float acc[ROWS][K_SZ];
#pragma unroll
  for (int r = 0; r < ROWS; ++r)
#pragma unroll
    for (int k = 0; k < K_SZ; ++k) acc[r][k] = 0.0f;

#define LOAD_X(dst, toff)                                                     \
  do {                                                                        \
    _Pragma("unroll")                                                         \
    for (int r_ = 0; r_ < ROWS; ++r_)                                         \
      dst[r_] = *reinterpret_cast<const float4*>(                             \
          xrow0 + (size_t)r_ * N_SZ + (toff) * W_STEP + 4 * lane);            \
  } while (0)

#define FILL_WT(bufi, toff)                                                   \
  do {                                                                        \
    const int nl_ = (toff) * W_STEP + tid;                                    \
    const float px_ = pb[3 * nl_ + 0];                                        \
    const float py_ = pb[3 * nl_ + 1];                                        \
    const float pz_ = pb[3 * nl_ + 2];                                        \
    _Pragma("unroll")                                                         \
    for (int k_ = 0; k_ < K_SZ; ++k_) {                                       \
      const float dx_ = px_ - kps[3 * k_ + 0];                                \
      const float dy_ = py_ - kps[3 * k_ + 1];                                \
      const float dz_ = pz_ - kps[3 * k_ + 2];                                \
      const float d_ = sqrtf(fmaf(dx_, dx_, fmaf(dy_, dy_, dz_ * dz_)));      \
      wt[bufi][k_][tid] = fmaxf(1.0f - d_ * INV_KP_EXTENT, 0.0f);             \
    }                                                                         \
  } while (0)

#define DO_FMA(xr, bufi)                                                      \
  do {                                                                        \
    _Pragma("unroll")                                                         \
    for (int k_ = 0; k_ < K_SZ; ++k_) {                                       \
      const float4 wq_ = *reinterpret_cast<const float4*>(&wt[bufi][k_][4 * lane]); \
      _Pragma("unroll")                                                       \
      for (int r_ = 0; r_ < ROWS; ++r_)                                       \
        acc[r_][k_] = fmaf(wq_.x, xr[r_].x,                                   \
                      fmaf(wq_.y, xr[r_].y,                                   \
                      fmaf(wq_.z, xr[r_].z,                                   \
                      fmaf(wq_.w, xr[r_].w, acc[r_][k_]))));                  \
    }                                                                         \
  } while (0)

  float4 xA[ROWS], xB[ROWS];
  __syncthreads();          // kps visible
  FILL_WT(0, 0);
  LOAD_X(xA, 0);
  __syncthreads();          // wt[0] ready

  for (int t = 0; t < STEPS; t += 2) {
    if (t + 1 < STEPS) {
      LOAD_X(xB, t + 1);
      FILL_WT(1, t + 1);
    }
    DO_FMA(xA, 0);
    __syncthreads();
    if (t + 1 < STEPS) {
      if (t + 2 < STEPS) {
        LOAD_X(xA, t + 2);
        FILL_WT(0, t + 2);
      }
      DO_FMA(xB, 1);
      __syncthreads();
    }
  }

  // epilogue: reduce each acc[r][k] across the 64 lanes (n-dimension);
  // lane k keeps value k of row r, lanes 0..14 store coalesced.
  float* pout = part + (size_t)blk * PART_PER_BLK + wid * (ROWS * K_SZ);
#pragma unroll
  for (int r = 0; r < ROWS; ++r) {
    float keep = 0.0f;
#pragma unroll
    for (int k = 0; k < K_SZ; ++k) {
      float v = acc[r][k];
      v += __shfl_xor(v, 1);
      v += __shfl_xor(v, 2);
      v += __shfl_xor(v, 4);
      v += __shfl_xor(v, 8);
      v += __shfl_xor(v, 16);
      v += __shfl_xor(v, 32);
      if (lane == k) keep = v;
    }
    if (lane < K_SZ) pout[r * K_SZ + lane] = keep;
  }
}

// part[blk][wid][r][k], blk = (b*G+cg)*S_SPANS + s, c = cg*32 + wid*8 + r.
__global__ __launch_bounds__(C_SZ) void kpconv_reduce_gemm(
    const float* __restrict__ part, const float* __restrict__ W,
    float* __restrict__ out) {
  const int k = blockIdx.x;   // 0..14
  const int b = blockIdx.y;   // 0..7
  const int tid = threadIdx.x;  // c
  __shared__ float row[C_SZ];

  const int cg = tid >> 5, wid = (tid >> 3) & 3, r = tid & 7;
  const size_t base = ((size_t)(b * G + cg) * S_SPANS) * PART_PER_BLK
                    + wid * (ROWS * K_SZ) + r * K_SZ + k;
  float sum = 0.0f;
  for (int ss = 0; ss < S_SPANS; ++ss)
    sum += part[base + (size_t)ss * PART_PER_BLK];
  row[tid] = sum;
  __syncthreads();

  float acc = 0.0f;
  const float* Wk = W + (size_t)k * C_SZ * C_SZ;
#pragma unroll 8
  for (int c = 0; c < C_SZ; ++c) acc += row[c] * Wk[(size_t)c * C_SZ + tid];
  atomicAdd(&out[b * C_SZ + tid], acc);
}

extern "C" void kernel_launch(void* const* d_in, const int* in_sizes, int n_in,
                              void* d_out, int out_size, void* d_ws, size_t ws_size,
                              hipStream_t stream) {
  const float* p  = (const float*)d_in[0];
  const float* x  = (const float*)d_in[1];
  const float* w  = (const float*)d_in[2];
  const float* kp = (const float*)d_in[3];
  float* out  = (float*)d_out;
  float* part = (float*)d_ws;  // needs B*G*S_SPANS*480*4 = ~2 MB

  hipMemsetAsync(d_out, 0, (size_t)out_size * sizeof(float), stream);
  kpconv_main<<<dim3(B_SZ * G * S_SPANS), THREADS, 0, stream>>>(p, x, kp, part);
  kpconv_reduce_gemm<<<dim3(K_SZ, B_SZ), C_SZ, 0, stream>>>(part, w, out);
}